// Round 2
// baseline (158.836 us; speedup 1.0000x reference)
//
#include <hip/hip_runtime.h>

// Problem constants
#define IC 8
#define NC 2304      // 48*48 coarse pixels (theta rows == phi cols, coarse)
#define NF 9216      // 96*96 fine pixels
#define Z_ELEMS 147456    // 16*96*96
#define XPAN_ELEMS 589824 // 16*192*192

typedef unsigned int uint_t;

// ---------------------------------------------------------------------------
// Kernel 1: theta conv (blocks 0..8), phi conv+pool (9..17), g conv+pool
// (18..53), x_pan passthrough copy (54..629).
// ---------------------------------------------------------------------------
__global__ __launch_bounds__(256) void k1_prep(
    const float* __restrict__ xms,    // (16,96,96)
    const float* __restrict__ hppan,  // (16,192,192)
    const float* __restrict__ xpan,   // (16,192,192)
    const float* __restrict__ gw, const float* __restrict__ gb,
    const float* __restrict__ thw, const float* __restrict__ thb,
    const float* __restrict__ phw, const float* __restrict__ phb,
    float* __restrict__ theta_c,  // [2304][8]
    float* __restrict__ phi_c,    // [2304][8]
    float* __restrict__ gmat,     // [9216][8]
    float* __restrict__ xpan_out)
{
    __shared__ float w[16][9][8];
    __shared__ float bias2[16];
    const int b = blockIdx.x;
    const int tid = threadIdx.x;

    if (b < 9) {
        // --- theta: conv3x3 s2 p1 on x_ms(16,96,96) -> (8,48,48) ---
        for (int i = tid; i < 1152; i += 256) {
            int co = i / 144, rem = i % 144;
            int ci = rem / 9, tap = rem % 9;
            w[ci][tap][co] = thw[i];   // thw OIHW: co*144+ci*9+tap
        }
        if (tid < 8) bias2[tid] = thb[tid];
        __syncthreads();
        int pix = b * 256 + tid;              // 0..2303
        int r = pix / 48, c = pix % 48;
        float acc[8];
        #pragma unroll
        for (int co = 0; co < 8; ++co) acc[co] = bias2[co];
        for (int ci = 0; ci < 16; ++ci) {
            const float* base = xms + ci * 9216;
            #pragma unroll
            for (int dr = 0; dr < 3; ++dr) {
                int ir = 2 * r + dr - 1;
                if (ir < 0) continue;          // only top edge OOB (max=95)
                #pragma unroll
                for (int dc = 0; dc < 3; ++dc) {
                    int ic = 2 * c + dc - 1;
                    if (ic < 0) continue;
                    float xv = base[ir * 96 + ic];
                    int tap = dr * 3 + dc;
                    #pragma unroll
                    for (int co = 0; co < 8; ++co) acc[co] += w[ci][tap][co] * xv;
                }
            }
        }
        #pragma unroll
        for (int co = 0; co < 8; ++co) theta_c[pix * 8 + co] = acc[co];
    } else if (b < 18) {
        // --- phi: conv3x3 s2 p1 on x_pan(16,192,192)->(8,96,96), maxpool2 ---
        for (int i = tid; i < 1152; i += 256) {
            int co = i / 144, rem = i % 144;
            int ci = rem / 9, tap = rem % 9;
            w[ci][tap][co] = phw[i];
        }
        if (tid < 8) bias2[tid] = phb[tid];
        __syncthreads();
        int pix = (b - 9) * 256 + tid;        // coarse 0..2303
        int rc = pix / 48, cc = pix % 48;
        float best[8];
        #pragma unroll
        for (int co = 0; co < 8; ++co) best[co] = -INFINITY;
        for (int sp = 0; sp < 4; ++sp) {
            int r96 = 2 * rc + (sp >> 1), c96 = 2 * cc + (sp & 1);
            float acc[8];
            #pragma unroll
            for (int co = 0; co < 8; ++co) acc[co] = 0.f;
            for (int ci = 0; ci < 16; ++ci) {
                const float* base = xpan + ci * 36864;
                #pragma unroll
                for (int dr = 0; dr < 3; ++dr) {
                    int ir = 2 * r96 + dr - 1;
                    if (ir < 0) continue;      // max = 191, in range
                    #pragma unroll
                    for (int dc = 0; dc < 3; ++dc) {
                        int icc = 2 * c96 + dc - 1;
                        if (icc < 0) continue;
                        float xv = base[ir * 192 + icc];
                        int tap = dr * 3 + dc;
                        #pragma unroll
                        for (int co = 0; co < 8; ++co) acc[co] += w[ci][tap][co] * xv;
                    }
                }
            }
            #pragma unroll
            for (int co = 0; co < 8; ++co) best[co] = fmaxf(best[co], acc[co]);
        }
        #pragma unroll
        for (int co = 0; co < 8; ++co) phi_c[pix * 8 + co] = best[co] + bias2[co];
    } else if (b < 54) {
        // --- g: conv1x1 on hp_pan(16,192,192)->(8,192,192), maxpool2 -> (8,96,96) ---
        for (int i = tid; i < 128; i += 256) {
            int co = i / 16, ci = i % 16;
            w[ci][0][co] = gw[i];              // gw: co*16+ci
        }
        if (tid < 8) bias2[tid] = gb[tid];
        __syncthreads();
        int pix = (b - 18) * 256 + tid;        // fine 0..9215
        int r = pix / 96, c = pix % 96;
        float best[8];
        #pragma unroll
        for (int co = 0; co < 8; ++co) best[co] = -INFINITY;
        for (int sp = 0; sp < 4; ++sp) {
            int ir = 2 * r + (sp >> 1), icc = 2 * c + (sp & 1);
            const float* bp = hppan + ir * 192 + icc;
            float acc[8];
            #pragma unroll
            for (int co = 0; co < 8; ++co) acc[co] = 0.f;
            for (int ci = 0; ci < 16; ++ci) {
                float xv = bp[ci * 36864];
                #pragma unroll
                for (int co = 0; co < 8; ++co) acc[co] += w[ci][0][co] * xv;
            }
            #pragma unroll
            for (int co = 0; co < 8; ++co) best[co] = fmaxf(best[co], acc[co]);
        }
        #pragma unroll
        for (int co = 0; co < 8; ++co) gmat[pix * 8 + co] = best[co] + bias2[co];
    } else {
        // --- x_pan passthrough: 589824 f32 = 147456 uint4 = 576 blocks ---
        int i = (b - 54) * 256 + tid;
        ((uint4*)xpan_out)[i] = ((const uint4*)xpan)[i];
    }
}

// ---------------------------------------------------------------------------
// Kernel 2: per coarse row nc, top-2 over 2304 coarse columns (stable,
// index-tiebreak = jax.lax.top_k semantics), then y_c[nc] = softmax-weighted
// g combination. One wave64 per row; 4 waves/block; 576 blocks.
// Top-5 of the fine row = 4 duplicated copies of the coarse max + first fine
// copy of the coarse runner-up; softmax weights collapse accordingly.
// ---------------------------------------------------------------------------
__global__ __launch_bounds__(256) void k2_attn(
    const float* __restrict__ theta_c, const float* __restrict__ phi_c,
    const float* __restrict__ gmat, float* __restrict__ y_c)
{
    const int wv = threadIdx.x >> 6, lane = threadIdx.x & 63;
    const int nc = blockIdx.x * 4 + wv;

    float th[8];
    #pragma unroll
    for (int j = 0; j < 8; ++j) th[j] = theta_c[nc * 8 + j];

    float v1 = -INFINITY, v2 = -INFINITY;
    int i1 = 0x7fffffff, i2 = 0x7fffffff;
    for (int it = 0; it < 36; ++it) {
        int mc = lane + (it << 6);
        const float4* p = (const float4*)(phi_c + mc * 8);
        float4 a = p[0], bq = p[1];
        float v = th[0] * a.x + th[1] * a.y + th[2] * a.z + th[3] * a.w
                + th[4] * bq.x + th[5] * bq.y + th[6] * bq.z + th[7] * bq.w;
        if (v > v1)      { v2 = v1; i2 = i1; v1 = v; i1 = mc; }
        else if (v > v2) { v2 = v; i2 = mc; }
        // exact tie with v1 falls into (v > v2): becomes v2 with the later
        // index; matches stable top_k ordering (per-lane indices ascend).
    }
    // butterfly merge of per-lane top-2 across the wave
    #pragma unroll
    for (int off = 1; off < 64; off <<= 1) {
        float ov1 = __shfl_xor(v1, off);
        int   oi1 = __shfl_xor(i1, off);
        float ov2 = __shfl_xor(v2, off);
        int   oi2 = __shfl_xor(i2, off);
        bool afirst = (v1 > ov1) || (v1 == ov1 && i1 < oi1);
        if (afirst) {
            bool t = (v2 > ov1) || (v2 == ov1 && i2 < oi1);
            v2 = t ? v2 : ov1; i2 = t ? i2 : oi1;
        } else {
            bool t = (ov2 > v1) || (ov2 == v1 && oi2 < i1);
            float nv2 = t ? ov2 : v1; int ni2 = t ? oi2 : i1;
            v1 = ov1; i1 = oi1; v2 = nv2; i2 = ni2;
        }
    }
    // all lanes converge to the same (v1,i1,v2,i2); lanes 0..7 do channels
    if (lane < 8) {
        int rc1 = i1 / 48, cc1 = i1 % 48;
        int m00 = (2 * rc1) * 96 + 2 * cc1;        // 4 fine copies of argmax
        int rc2 = i2 / 48, cc2 = i2 % 48;
        int m2  = (2 * rc2) * 96 + 2 * cc2;        // first fine copy of 2nd
        float e = __expf(v2 - v1);
        float inv = 1.0f / (4.0f + e);
        float gs = gmat[m00 * 8 + lane] + gmat[(m00 + 1) * 8 + lane]
                 + gmat[(m00 + 96) * 8 + lane] + gmat[(m00 + 97) * 8 + lane];
        y_c[nc * 8 + lane] = inv * gs + (e * inv) * gmat[m2 * 8 + lane];
    }
}

// ---------------------------------------------------------------------------
// Kernel 3: wy = W(y)+b per channel (block co owns the whole channel),
// batch stats over the 2304 coarse pixels (== fine stats: y constant over
// 2x2 blocks), normalize, write z upsampled 2x as fp32.
// ---------------------------------------------------------------------------
__global__ __launch_bounds__(256) void k3_out(
    const float* __restrict__ y_c,
    const float* __restrict__ Ww, const float* __restrict__ Wb,
    const float* __restrict__ gamma, const float* __restrict__ beta,
    float* __restrict__ zout)
{
    const int co = blockIdx.x;
    const int tid = threadIdx.x;
    float w[8];
    #pragma unroll
    for (int j = 0; j < 8; ++j) w[j] = Ww[co * 8 + j];
    const float bias = Wb[co];

    float wy[9];
    float s = 0.f, s2 = 0.f;
    #pragma unroll
    for (int j = 0; j < 9; ++j) {
        int mc = tid + j * 256;                 // 2304 = 9*256 exactly
        const float4* p = (const float4*)(y_c + mc * 8);
        float4 a = p[0], bq = p[1];
        float v = bias + w[0] * a.x + w[1] * a.y + w[2] * a.z + w[3] * a.w
                       + w[4] * bq.x + w[5] * bq.y + w[6] * bq.z + w[7] * bq.w;
        wy[j] = v; s += v; s2 += v * v;
    }
    #pragma unroll
    for (int off = 32; off; off >>= 1) {
        s  += __shfl_down(s, off);
        s2 += __shfl_down(s2, off);
    }
    __shared__ float ps[4], ps2[4];
    __shared__ float sc_s, sh_s;
    int wv = tid >> 6, lane = tid & 63;
    if (lane == 0) { ps[wv] = s; ps2[wv] = s2; }
    __syncthreads();
    if (tid == 0) {
        float S  = ps[0] + ps[1] + ps[2] + ps[3];
        float S2 = ps2[0] + ps2[1] + ps2[2] + ps2[3];
        float mean = S * (1.0f / 2304.0f);
        float var  = S2 * (1.0f / 2304.0f) - mean * mean;
        float rsig = 1.0f / sqrtf(var + 1e-5f);
        float gm = gamma[co], be = beta[co];
        sc_s = gm * rsig;
        sh_s = be - mean * gm * rsig;
    }
    __syncthreads();
    float sc = sc_s, sh = sh_s;
    #pragma unroll
    for (int j = 0; j < 9; ++j) {
        int mc = tid + j * 256;
        int rc = mc / 48, cc = mc % 48;
        float zv = wy[j] * sc + sh;
        float2 zz = make_float2(zv, zv);         // 2 adjacent cols, same value
        int base = co * 9216 + (2 * rc) * 96 + 2 * cc;  // even -> 8B aligned
        *(float2*)(zout + base) = zz;
        *(float2*)(zout + base + 96) = zz;
    }
}

extern "C" void kernel_launch(void* const* d_in, const int* in_sizes, int n_in,
                              void* d_out, int out_size, void* d_ws, size_t ws_size,
                              hipStream_t stream) {
    const float* xms   = (const float*)d_in[0];
    const float* hppan = (const float*)d_in[1];
    const float* xpan  = (const float*)d_in[2];
    const float* gw    = (const float*)d_in[3];
    const float* gb    = (const float*)d_in[4];
    const float* thw   = (const float*)d_in[5];
    const float* thb   = (const float*)d_in[6];
    const float* phw   = (const float*)d_in[7];
    const float* phb   = (const float*)d_in[8];
    const float* Ww    = (const float*)d_in[9];
    const float* Wb    = (const float*)d_in[10];
    const float* gam   = (const float*)d_in[11];
    const float* bet   = (const float*)d_in[12];

    float* zout     = (float*)d_out;
    float* xpan_out = zout + Z_ELEMS;

    float* theta_c = (float*)d_ws;              // 18432 f32
    float* phi_c   = theta_c + NC * IC;         // 18432 f32
    float* gmat    = phi_c + NC * IC;           // 73728 f32
    float* y_c     = gmat + NF * IC;            // 18432 f32  (total ~516 KB)

    k1_prep<<<630, 256, 0, stream>>>(xms, hppan, xpan, gw, gb, thw, thb,
                                     phw, phb, theta_c, phi_c, gmat, xpan_out);
    k2_attn<<<576, 256, 0, stream>>>(theta_c, phi_c, gmat, y_c);
    k3_out<<<16, 256, 0, stream>>>(y_c, Ww, Wb, gam, bet, zout);
}

// Round 3
// 115.022 us; speedup vs baseline: 1.3809x; 1.3809x over previous
//
#include <hip/hip_runtime.h>

// Problem constants
#define IC 8
#define NC 2304      // 48*48 coarse pixels (theta rows == phi cols, coarse)
#define NF 9216      // 96*96 fine pixels
#define Z_ELEMS 147456    // 16*96*96
#define XPAN_ELEMS 589824 // 16*192*192

typedef unsigned int uint_t;

// ---------------------------------------------------------------------------
// Kernel 1:
//   blocks 0..8     theta conv3x3 s2 p1 (one thread per coarse output pixel)
//   blocks 9..44    phi conv3x3 s2 p1 (one thread per PRE-POOL pixel) + shfl-maxpool
//   blocks 45..188  g conv1x1 (one thread per PRE-POOL pixel) + shfl-maxpool
//   blocks 189..764 x_pan passthrough copy (uint4)
// All loads unconditional (clamp+select masks) so the compiler batches them;
// weights fetched with block-uniform indices -> scalar loads (K$), no LDS.
// ---------------------------------------------------------------------------
__global__ __launch_bounds__(256) void k1_prep(
    const float* __restrict__ xms,    // (16,96,96)
    const float* __restrict__ hppan,  // (16,192,192)
    const float* __restrict__ xpan,   // (16,192,192)
    const float* __restrict__ gw, const float* __restrict__ gb,
    const float* __restrict__ thw, const float* __restrict__ thb,
    const float* __restrict__ phw, const float* __restrict__ phb,
    float* __restrict__ theta_c,  // [2304][8]
    float* __restrict__ phi_c,    // [2304][8]
    float* __restrict__ gmat,     // [9216][8]
    float* __restrict__ xpan_out)
{
    const int b = blockIdx.x;
    const int tid = threadIdx.x;

    if (b < 9) {
        // --- theta: (16,96,96) -> (8,48,48), one thread per output pixel ---
        int pix = b * 256 + tid;              // 0..2303
        int r = pix / 48, c = pix % 48;
        int ir0 = 2 * r - 1, ic0 = 2 * c - 1;
        bool rok = (r > 0), cok = (c > 0);
        float acc[8];
        #pragma unroll
        for (int co = 0; co < 8; ++co) acc[co] = thb[co];
        #pragma unroll 4
        for (int ci = 0; ci < 16; ++ci) {
            const float* base = xms + ci * 9216;
            float xv[9];
            #pragma unroll
            for (int dr = 0; dr < 3; ++dr) {
                #pragma unroll
                for (int dc = 0; dc < 3; ++dc) {
                    bool ok = (dr > 0 || rok) && (dc > 0 || cok);
                    int off = (ir0 + dr) * 96 + (ic0 + dc);
                    float v = base[ok ? off : 0];
                    xv[dr * 3 + dc] = ok ? v : 0.0f;
                }
            }
            #pragma unroll
            for (int tap = 0; tap < 9; ++tap) {
                #pragma unroll
                for (int co = 0; co < 8; ++co)
                    acc[co] += thw[co * 144 + ci * 9 + tap] * xv[tap];
            }
        }
        #pragma unroll
        for (int co = 0; co < 8; ++co) theta_c[pix * 8 + co] = acc[co];
    } else if (b < 45) {
        // --- phi: (16,192,192) -> conv (8,96,96) -> pool (8,48,48) ---
        // one thread per pre-pool pixel; pool-mates are lane quads
        int idx = (b - 9) * 256 + tid;        // 0..9215
        int cp = idx >> 2, sp = idx & 3;      // coarse pixel, subpixel
        int rc = cp / 48, cc = cp % 48;
        int r96 = 2 * rc + (sp >> 1), c96 = 2 * cc + (sp & 1);
        int ir0 = 2 * r96 - 1, ic0 = 2 * c96 - 1;
        bool rok = (r96 > 0), cok = (c96 > 0);
        float acc[8];
        #pragma unroll
        for (int co = 0; co < 8; ++co) acc[co] = 0.0f;
        #pragma unroll 4
        for (int ci = 0; ci < 16; ++ci) {
            const float* base = xpan + ci * 36864;
            float xv[9];
            #pragma unroll
            for (int dr = 0; dr < 3; ++dr) {
                #pragma unroll
                for (int dc = 0; dc < 3; ++dc) {
                    bool ok = (dr > 0 || rok) && (dc > 0 || cok);
                    int off = (ir0 + dr) * 192 + (ic0 + dc);
                    float v = base[ok ? off : 0];
                    xv[dr * 3 + dc] = ok ? v : 0.0f;
                }
            }
            #pragma unroll
            for (int tap = 0; tap < 9; ++tap) {
                #pragma unroll
                for (int co = 0; co < 8; ++co)
                    acc[co] += phw[co * 144 + ci * 9 + tap] * xv[tap];
            }
        }
        #pragma unroll
        for (int co = 0; co < 8; ++co) {
            float v = acc[co];
            v = fmaxf(v, __shfl_xor(v, 1));
            v = fmaxf(v, __shfl_xor(v, 2));
            if (sp == 0) phi_c[cp * 8 + co] = v + phb[co];
        }
    } else if (b < 189) {
        // --- g: 1x1 conv on (16,192,192) -> pool -> (8,96,96) ---
        int idx = (b - 45) * 256 + tid;       // 0..36863
        int op = idx >> 2, sp = idx & 3;      // output pixel (96x96), subpixel
        int r = 2 * (op / 96) + (sp >> 1), c = 2 * (op % 96) + (sp & 1);
        const float* bp = hppan + r * 192 + c;
        float acc[8];
        #pragma unroll
        for (int co = 0; co < 8; ++co) acc[co] = 0.0f;
        #pragma unroll
        for (int ci = 0; ci < 16; ++ci) {
            float xv = bp[ci * 36864];
            #pragma unroll
            for (int co = 0; co < 8; ++co)
                acc[co] += gw[co * 16 + ci] * xv;
        }
        #pragma unroll
        for (int co = 0; co < 8; ++co) {
            float v = acc[co];
            v = fmaxf(v, __shfl_xor(v, 1));
            v = fmaxf(v, __shfl_xor(v, 2));
            if (sp == 0) gmat[op * 8 + co] = v + gb[co];
        }
    } else {
        // --- x_pan passthrough: 589824 f32 = 147456 uint4 = 576 blocks ---
        int i = (b - 189) * 256 + tid;
        ((uint4*)xpan_out)[i] = ((const uint4*)xpan)[i];
    }
}

// ---------------------------------------------------------------------------
// Kernel 2: per coarse row nc, top-2 over 2304 coarse columns (stable,
// index-tiebreak = jax.lax.top_k semantics), then y_c[nc] = softmax-weighted
// g combination. phi_c (72 KB) staged in LDS once per block; 4 rows/block.
// Top-5 of the fine row = 4 duplicated copies of the coarse max + first fine
// copy of the coarse runner-up; softmax weights collapse accordingly.
// ---------------------------------------------------------------------------
__global__ __launch_bounds__(256) void k2_attn(
    const float* __restrict__ theta_c, const float* __restrict__ phi_c,
    const float* __restrict__ gmat, float* __restrict__ y_c)
{
    __shared__ float4 ph4[NC * 2];            // 2304 * 32 B = 72 KB
    const int tid = threadIdx.x;
    const float4* src = (const float4*)phi_c;
    #pragma unroll
    for (int j = 0; j < 18; ++j)              // 4608 float4 / 256 threads
        ph4[tid + j * 256] = src[tid + j * 256];
    __syncthreads();

    const int wv = tid >> 6, lane = tid & 63;
    const int nc = __builtin_amdgcn_readfirstlane(blockIdx.x * 4 + wv);

    float th[8];
    #pragma unroll
    for (int j = 0; j < 8; ++j) th[j] = theta_c[nc * 8 + j];  // uniform -> s_load

    float v1 = -INFINITY, v2 = -INFINITY;
    int i1 = 0x7fffffff, i2 = 0x7fffffff;
    #pragma unroll 4
    for (int it = 0; it < 36; ++it) {
        int mc = lane + (it << 6);
        float4 a = ph4[mc * 2], bq = ph4[mc * 2 + 1];
        float v = th[0] * a.x + th[1] * a.y + th[2] * a.z + th[3] * a.w
                + th[4] * bq.x + th[5] * bq.y + th[6] * bq.z + th[7] * bq.w;
        if (v > v1)      { v2 = v1; i2 = i1; v1 = v; i1 = mc; }
        else if (v > v2) { v2 = v; i2 = mc; }
        // exact tie with v1 falls into (v > v2): becomes v2 with the later
        // index; matches stable top_k ordering (per-lane indices ascend).
    }
    // butterfly merge of per-lane top-2 across the wave
    #pragma unroll
    for (int off = 1; off < 64; off <<= 1) {
        float ov1 = __shfl_xor(v1, off);
        int   oi1 = __shfl_xor(i1, off);
        float ov2 = __shfl_xor(v2, off);
        int   oi2 = __shfl_xor(i2, off);
        bool afirst = (v1 > ov1) || (v1 == ov1 && i1 < oi1);
        if (afirst) {
            bool t = (v2 > ov1) || (v2 == ov1 && i2 < oi1);
            v2 = t ? v2 : ov1; i2 = t ? i2 : oi1;
        } else {
            bool t = (ov2 > v1) || (ov2 == v1 && oi2 < i1);
            float nv2 = t ? ov2 : v1; int ni2 = t ? oi2 : i1;
            v1 = ov1; i1 = oi1; v2 = nv2; i2 = ni2;
        }
    }
    // all lanes converge to the same (v1,i1,v2,i2); lanes 0..7 do channels
    if (lane < 8) {
        int rc1 = i1 / 48, cc1 = i1 % 48;
        int m00 = (2 * rc1) * 96 + 2 * cc1;        // 4 fine copies of argmax
        int rc2 = i2 / 48, cc2 = i2 % 48;
        int m2  = (2 * rc2) * 96 + 2 * cc2;        // first fine copy of 2nd
        float e = __expf(v2 - v1);
        float inv = 1.0f / (4.0f + e);
        float gs = gmat[m00 * 8 + lane] + gmat[(m00 + 1) * 8 + lane]
                 + gmat[(m00 + 96) * 8 + lane] + gmat[(m00 + 97) * 8 + lane];
        y_c[nc * 8 + lane] = inv * gs + (e * inv) * gmat[m2 * 8 + lane];
    }
}

// ---------------------------------------------------------------------------
// Kernel 3: wy = W(y)+b per channel (block co owns the whole channel),
// batch stats over the 2304 coarse pixels (== fine stats: y constant over
// 2x2 blocks), normalize, write z upsampled 2x as fp32.
// ---------------------------------------------------------------------------
__global__ __launch_bounds__(256) void k3_out(
    const float* __restrict__ y_c,
    const float* __restrict__ Ww, const float* __restrict__ Wb,
    const float* __restrict__ gamma, const float* __restrict__ beta,
    float* __restrict__ zout)
{
    const int co = blockIdx.x;
    const int tid = threadIdx.x;
    float w[8];
    #pragma unroll
    for (int j = 0; j < 8; ++j) w[j] = Ww[co * 8 + j];
    const float bias = Wb[co];

    float wy[9];
    float s = 0.f, s2 = 0.f;
    #pragma unroll
    for (int j = 0; j < 9; ++j) {
        int mc = tid + j * 256;                 // 2304 = 9*256 exactly
        const float4* p = (const float4*)(y_c + mc * 8);
        float4 a = p[0], bq = p[1];
        float v = bias + w[0] * a.x + w[1] * a.y + w[2] * a.z + w[3] * a.w
                       + w[4] * bq.x + w[5] * bq.y + w[6] * bq.z + w[7] * bq.w;
        wy[j] = v; s += v; s2 += v * v;
    }
    #pragma unroll
    for (int off = 32; off; off >>= 1) {
        s  += __shfl_down(s, off);
        s2 += __shfl_down(s2, off);
    }
    __shared__ float ps[4], ps2[4];
    __shared__ float sc_s, sh_s;
    int wv = tid >> 6, lane = tid & 63;
    if (lane == 0) { ps[wv] = s; ps2[wv] = s2; }
    __syncthreads();
    if (tid == 0) {
        float S  = ps[0] + ps[1] + ps[2] + ps[3];
        float S2 = ps2[0] + ps2[1] + ps2[2] + ps2[3];
        float mean = S * (1.0f / 2304.0f);
        float var  = S2 * (1.0f / 2304.0f) - mean * mean;
        float rsig = 1.0f / sqrtf(var + 1e-5f);
        float gm = gamma[co], be = beta[co];
        sc_s = gm * rsig;
        sh_s = be - mean * gm * rsig;
    }
    __syncthreads();
    float sc = sc_s, sh = sh_s;
    #pragma unroll
    for (int j = 0; j < 9; ++j) {
        int mc = tid + j * 256;
        int rc = mc / 48, cc = mc % 48;
        float zv = wy[j] * sc + sh;
        float2 zz = make_float2(zv, zv);         // 2 adjacent cols, same value
        int base = co * 9216 + (2 * rc) * 96 + 2 * cc;  // even -> 8B aligned
        *(float2*)(zout + base) = zz;
        *(float2*)(zout + base + 96) = zz;
    }
}

extern "C" void kernel_launch(void* const* d_in, const int* in_sizes, int n_in,
                              void* d_out, int out_size, void* d_ws, size_t ws_size,
                              hipStream_t stream) {
    const float* xms   = (const float*)d_in[0];
    const float* hppan = (const float*)d_in[1];
    const float* xpan  = (const float*)d_in[2];
    const float* gw    = (const float*)d_in[3];
    const float* gb    = (const float*)d_in[4];
    const float* thw   = (const float*)d_in[5];
    const float* thb   = (const float*)d_in[6];
    const float* phw   = (const float*)d_in[7];
    const float* phb   = (const float*)d_in[8];
    const float* Ww    = (const float*)d_in[9];
    const float* Wb    = (const float*)d_in[10];
    const float* gam   = (const float*)d_in[11];
    const float* bet   = (const float*)d_in[12];

    float* zout     = (float*)d_out;
    float* xpan_out = zout + Z_ELEMS;

    float* theta_c = (float*)d_ws;              // 18432 f32
    float* phi_c   = theta_c + NC * IC;         // 18432 f32
    float* gmat    = phi_c + NC * IC;           // 73728 f32
    float* y_c     = gmat + NF * IC;            // 18432 f32  (total ~516 KB)

    k1_prep<<<765, 256, 0, stream>>>(xms, hppan, xpan, gw, gb, thw, thb,
                                     phw, phb, theta_c, phi_c, gmat, xpan_out);
    k2_attn<<<576, 256, 0, stream>>>(theta_c, phi_c, gmat, y_c);
    k3_out<<<16, 256, 0, stream>>>(y_c, Ww, Wb, gam, bet, zout);
}